// Round 6
// baseline (211.292 us; speedup 1.0000x reference)
//
#include <hip/hip_runtime.h>

typedef _Float16 f16;
typedef _Float16 half2v __attribute__((ext_vector_type(2)));
typedef _Float16 half4v __attribute__((ext_vector_type(4)));
typedef _Float16 half8 __attribute__((ext_vector_type(8)));
typedef float f32x4 __attribute__((ext_vector_type(4)));
typedef unsigned u32x4 __attribute__((ext_vector_type(4)));

#define MFMA16(a, b, c) __builtin_amdgcn_mfma_f32_16x16x32_f16((a), (b), (c), 0, 0, 0)

__device__ __forceinline__ unsigned pk2(float a, float b) {
  return __builtin_bit_cast(unsigned, __builtin_amdgcn_cvt_pkrtz(a, b));
}

// Cross-quad redistribution for P (QK^T C-layout -> PV A-layout):
//   permlane32_swap: vdst.{q2,q3} <-> vsrc.{q0,q1}
//   permlane16_swap: vdst.{q1,q3} <-> vsrc.{q0,q2}
__device__ __forceinline__ void plswap_pair(unsigned& a, unsigned& b) {
  asm("s_nop 1\n\t"
      "v_permlane32_swap_b32 %0, %1\n\t"
      "v_permlane16_swap_b32 %0, %1"
      : "+v"(a), "+v"(b));
}

// Sizes: B=4, CI=64, H=W=128 ; conv out 64x64 ; C=160 ; S=4097 ; SQ=4096 ; NH=4 ; HD=40
// R15 finding: harness re-poisons the FULL 256 MiB workspace every iteration
// (fillBufferAligned, WRITE_SIZE=262144 KiB, ~45 us @6 TB/s) INSIDE the timed region.
// That fixed cost + ~80 us of small aux kernels/launch gaps is the "invariant residual";
// k_attn (75 us) is the only large attackable item.
// R16: k_attn occupancy x2 at constant memory footprint: same grid (32,16,2), same 1024
// blocks, same pacc windows (no RMW, no extra slices -> no R12-style L2 write thrash),
// but 8 waves x 16 q per block (512 threads) instead of 4 x 32. Waves/CU 16 -> 32.
// Trade: K/V-frag LDS reads per MFMA double (~45 TB/s, under 69 ceiling); phase-B VALU
// per wave halves. Diagnostic split reverted (single k_attn launch).

// ---------------- K0: convert wq/wk/wv f32 -> f16 [kind][160][160] -------------------
__global__ __launch_bounds__(256) void k_prep(
    const float* __restrict__ wq, const float* __restrict__ wk,
    const float* __restrict__ wv, f16* __restrict__ wf) {
  int kind = blockIdx.y;
  const float* src = (kind == 0) ? wq : (kind == 1 ? wk : wv);
  int i4 = blockIdx.x * 256 + threadIdx.x;  // [0,6400)
  f32x4 v = *(const f32x4*)(src + i4 * 4);
  uint2 u = {pk2(v[0], v[1]), pk2(v[2], v[3])};
  *(uint2*)(wf + (size_t)kind * 25600 + i4 * 4) = u;
}

// ---------------- K1: conv1(MFMA) -> conv2(MFMA)+leaky+pe -> fh + pad row ---------------
__global__ __launch_bounds__(256) void k_conv(
    const float* __restrict__ x, const float* __restrict__ w1, const float* __restrict__ b1,
    const float* __restrict__ w2, const float* __restrict__ b2, const float* __restrict__ pe,
    const float* __restrict__ wq, const float* __restrict__ wk, const float* __restrict__ wv,
    f16* __restrict__ fh, f16* __restrict__ q_h, f16* __restrict__ k_h,
    f16* __restrict__ vt_h, float* __restrict__ kmaxp) {
  // LDS map:
  //   [0,21504)        fT   64x168 f16   (conv2 out)
  //   [21504,55360)    xh   64x264 f16 [pos][ciq]
  //   [55360,89152)    w1h  64x264 f16 [co][ciq]  | post-conv1 overlay: c1t 64x72 [pos][co]
  //                                                | + red160 (pad-row knorm) at +9216
  //   [89152,112192)   w2h 160x72 f16 [c2][co]
  __shared__ __attribute__((aligned(16))) char smem[112192];
  f16* fT   = (f16*)smem;
  f16* xh   = (f16*)(smem + 21504);
  f16* w1h  = (f16*)(smem + 55360);
  f16* c1t  = (f16*)(smem + 55360);
  float* red160 = (float*)(smem + 64576);
  f16* w2h  = (f16*)(smem + 89152);

  const float c1l = 0.15811388300841898f * 1.4426950408889634f;  // scale*log2e

  int y = blockIdx.x, b = blockIdx.y;
  int t = threadIdx.x, lane = t & 63, wv4 = t >> 6, quad = lane >> 4, col = lane & 15;
  int s0 = y * 64;

  // ---- phase 1: stage xh (f32->f16, B layout), w1h, w2h ----
  const float* xb = x + (b * 64) * 16384 + (2 * y) * 128;
#pragma unroll
  for (int it = 0; it < 32; ++it) {
    int flat = t + it * 256;  // [0,8192) float2 units
    int pos = flat & 63, r = (flat >> 6) & 1, ci = flat >> 7;
    float2 v = *(const float2*)(xb + ci * 16384 + r * 128 + 2 * pos);
    *(unsigned*)(xh + pos * 264 + ci * 4 + r * 2) = pk2(v.x, v.y);
  }
#pragma unroll
  for (int it = 0; it < 16; ++it) {
    int i4 = t + it * 256;  // [0,4096) f32x4 units of w1 (64x256)
    int co = i4 >> 6, q4 = (i4 & 63) * 4;
    f32x4 v = *(const f32x4*)(w1 + co * 256 + q4);
    uint2 u = {pk2(v[0], v[1]), pk2(v[2], v[3])};
    *(uint2*)(w1h + co * 264 + q4) = u;
  }
#pragma unroll
  for (int it = 0; it < 10; ++it) {
    int i4 = t + it * 256;  // [0,2560) f32x4 units of w2 (160x64)
    int c2 = i4 >> 4, q4 = (i4 & 15) * 4;
    f32x4 v = *(const f32x4*)(w2 + c2 * 64 + q4);
    uint2 u = {pk2(v[0], v[1]), pk2(v[2], v[3])};
    *(uint2*)(w2h + c2 * 72 + q4) = u;
  }
  __syncthreads();

  // ---- phase 2: conv1 MFMA  c1[co][pos] = w1h[co][.] . xh[pos][.] + b1 ----
  float b1v[4];
#pragma unroll
  for (int r = 0; r < 4; ++r) b1v[r] = b1[wv4 * 16 + quad * 4 + r];
  f32x4 acc1[4];
#pragma unroll
  for (int nt = 0; nt < 4; ++nt)
#pragma unroll
    for (int r = 0; r < 4; ++r) acc1[nt][r] = b1v[r];
#pragma unroll
  for (int kk = 0; kk < 8; ++kk) {
    half8 a = *(half8*)(w1h + (wv4 * 16 + col) * 264 + kk * 32 + quad * 8);
#pragma unroll
    for (int nt = 0; nt < 4; ++nt) {
      half8 bfr = *(half8*)(xh + (nt * 16 + col) * 264 + kk * 32 + quad * 8);
      acc1[nt] = MFMA16(a, bfr, acc1[nt]);
    }
  }
  __syncthreads();  // all w1h reads done before c1t overlay
#pragma unroll
  for (int nt = 0; nt < 4; ++nt) {
    uint2 u = {pk2(acc1[nt][0], acc1[nt][1]), pk2(acc1[nt][2], acc1[nt][3])};
    *(uint2*)(c1t + (nt * 16 + col) * 72 + wv4 * 16 + quad * 4) = u;
  }
  __syncthreads();

  // ---- phase 3: conv2 MFMA  f[pos][c2] = leaky(w2h[c2][.] . c1t[pos][.] + b2) + pe ----
  f32x4 acc2[10];
#pragma unroll
  for (int mt = 0; mt < 10; ++mt)
#pragma unroll
    for (int r = 0; r < 4; ++r) acc2[mt][r] = b2[mt * 16 + quad * 4 + r];
  half8 bb0 = *(half8*)(c1t + (wv4 * 16 + col) * 72 + quad * 8);
  half8 bb1 = *(half8*)(c1t + (wv4 * 16 + col) * 72 + 32 + quad * 8);
#pragma unroll
  for (int mt = 0; mt < 10; ++mt) {
    half8 a0 = *(half8*)(w2h + (mt * 16 + col) * 72 + quad * 8);
    half8 a1 = *(half8*)(w2h + (mt * 16 + col) * 72 + 32 + quad * 8);
    acc2[mt] = MFMA16(a0, bb0, acc2[mt]);
    acc2[mt] = MFMA16(a1, bb1, acc2[mt]);
  }
  float pes = pe[s0 + wv4 * 16 + col];
#pragma unroll
  for (int mt = 0; mt < 10; ++mt) {
    float p[4];
#pragma unroll
    for (int r = 0; r < 4; ++r) {
      float v = acc2[mt][r];
      v = (v >= 0.f) ? v : 0.01f * v;  // leaky BEFORE pe add
      p[r] = v + pes;
    }
    uint2 u = {pk2(p[0], p[1]), pk2(p[2], p[3])};
    *(uint2*)(fT + (wv4 * 16 + col) * 168 + mt * 16 + quad * 4) = u;
  }
  __syncthreads();

  // ---- phase 4: write fh[b][s][160] f16 (coalesced uint4) ----
#pragma unroll
  for (int it = 0; it < 5; ++it) {
    int flat = t + it * 256;  // [0,1280)
    int row = flat / 20, seg = flat - row * 20;
    *(uint4*)(fh + ((size_t)b * 4096 + s0 + row) * 160 + seg * 8) =
        *(const uint4*)(fT + row * 168 + seg * 8);
  }

  // ---- pad row s=4096: f[4096][c] = pe[4096] for all c => qkv = pe4096 * rowsum(W) ----
  if (y == 63) {
    float pe4 = pe[4096];
    if (t < 160) {
      int hh = t / 40, d = t - hh * 40, bh = b * 4 + hh;
#pragma unroll
      for (int kind = 0; kind < 3; ++kind) {
        const float* wsp = (kind == 0) ? wq : (kind == 1 ? wk : wv);
        const float* wr = wsp + t * 160;
        float rs = 0.f;
#pragma unroll
        for (int c4 = 0; c4 < 40; ++c4) {
          f32x4 v = *(const f32x4*)(wr + c4 * 4);
          rs += v[0] + v[1] + v[2] + v[3];
        }
        float val = pe4 * rs;
        if (kind == 0)      q_h[((size_t)bh * 4097 + 4096) * 40 + d] = (f16)(val * c1l);
        else if (kind == 1) { k_h[((size_t)bh * 4160 + 4096) * 40 + d] = (f16)val;
                              red160[t] = val * val; }
        else                vt_h[((size_t)bh * 40 + d) * 4160 + 4096] = (f16)val;
      }
    }
    __syncthreads();
    if (t < 4) {
      float s = 0.f;
#pragma unroll
      for (int j = 0; j < 40; ++j) s += red160[t * 40 + j];
      kmaxp[(b * 4 + t) * 65 + 64] = s;
    }
  }
}

// ---------------- K1b: QKV GEMM, both operands direct from global f16 -------------------
__global__ __launch_bounds__(256) void k_qkv(
    const f16* __restrict__ fh, const f16* __restrict__ wf,
    f16* __restrict__ q_h, f16* __restrict__ k_h, f16* __restrict__ vt_h) {
  __shared__ __attribute__((aligned(16))) f16 Lv[160 * 72];
  int y = blockIdx.x, b = blockIdx.y, kind = blockIdx.z;
  int t = threadIdx.x, lane = t & 63, wvv = t >> 6, quad = lane >> 4, col = lane & 15;
  int s0 = y * 64;
  const float c1l = 0.15811388300841898f * 1.4426950408889634f;  // scale*log2e
  const f16* wk_ = wf + (size_t)kind * 25600;

  half8 af[5];
  int rowA = wvv * 16 + col;
#pragma unroll
  for (int kk = 0; kk < 5; ++kk)
    af[kk] = *(const half8*)(fh + ((size_t)b * 4096 + s0 + rowA) * 160 + kk * 32 + quad * 8);

#pragma unroll
  for (int n0 = 0; n0 < 10; ++n0) {
    f32x4 acc; acc[0] = 0.f; acc[1] = 0.f; acc[2] = 0.f; acc[3] = 0.f;
    int rowB = n0 * 16 + col;
#pragma unroll
    for (int kk = 0; kk < 5; ++kk) {
      half8 bf = *(const half8*)(wk_ + rowB * 160 + kk * 32 + quad * 8);
      acc = MFMA16(af[kk], bf, acc);
    }
    int o = n0 * 16 + col;
    int hh = o / 40, d = o - hh * 40;
    int bh = b * 4 + hh;
    if (kind == 2) {
      half4v hv;
#pragma unroll
      for (int r = 0; r < 4; ++r) hv[r] = (f16)acc[r];
      *(half4v*)(Lv + o * 72 + wvv * 16 + quad * 4) = hv;
    } else {
#pragma unroll
      for (int r = 0; r < 4; ++r) {
        int s = s0 + wvv * 16 + quad * 4 + r;  // <= 4095
        if (kind == 0) q_h[((size_t)bh * 4097 + s) * 40 + d] = (f16)(acc[r] * c1l);
        else           k_h[((size_t)bh * 4160 + s) * 40 + d] = (f16)acc[r];
      }
    }
  }
  if (kind == 2) {
    __syncthreads();
#pragma unroll
    for (int it = 0; it < 5; ++it) {
      int c = t + it * 256;  // [0,1280): 160 rows x 8 uint4 segs
      int row = c >> 3, seg = c & 7;
      int hh = row / 40, d = row - hh * 40;
      *(uint4*)(vt_h + ((size_t)(b * 4 + hh) * 40 + d) * 4160 + s0 + seg * 8) =
          *(const uint4*)(Lv + row * 72 + seg * 8);
    }
  }
}

// ---------------- K1c: kmaxp slots 0..63 from k_h ---------------------------------------
__global__ __launch_bounds__(256) void k_sq(
    const f16* __restrict__ k_h, float* __restrict__ kmaxp) {
  int t = threadIdx.x, lane = t & 63, wvv = t >> 6;
  int slot = blockIdx.x * 4 + wvv;  // 0..63
  int bh = blockIdx.y;
  int s = slot * 64 + lane;
  const f16* kr = k_h + ((size_t)bh * 4160 + s) * 40;
  float sum = 0.f;
#pragma unroll
  for (int i = 0; i < 5; ++i) {
    half8 v = *(const half8*)(kr + i * 8);
#pragma unroll
    for (int j = 0; j < 8; ++j) { float xv = (float)v[j]; sum += xv * xv; }
  }
#pragma unroll
  for (int d = 1; d < 64; d <<= 1) sum = fmaxf(sum, __shfl_xor(sum, d));
  if (lane == 0) kmaxp[bh * 65 + slot] = sum;
}

// ---------------- K2: flash attention, 8 waves x 16 q, K-split x2, K+V LDS dbuf ---------
// grid (32 qt, 16 bh, 2 ks) = 1024 blocks x 512 threads -> 4 blocks/CU, 32 waves/CU.
// Same pacc windows / K-V fetch as the 4-wave version; only wave decomposition changed.
__global__ __launch_bounds__(512, 6) void k_attn(
    const f16* __restrict__ q_h, const f16* __restrict__ k_h,
    const f16* __restrict__ vt_h, const float* __restrict__ kmaxp,
    float* __restrict__ pacc) {
  __shared__ __attribute__((aligned(16))) f16 Ks[2][64 * 40];
  __shared__ __attribute__((aligned(16))) f16 Vs[2][40 * 72];
  __shared__ __attribute__((aligned(16))) f16 Ones[8];
  __shared__ __attribute__((aligned(16))) f16 Zro[8];
  __shared__ __attribute__((aligned(16))) float red8[8];

  int qt = blockIdx.x, bh = blockIdx.y, ks = blockIdx.z;
  int qbase = qt * 128;
  int t = threadIdx.x, lane = t & 63, wid = t >> 6, quad = lane >> 4, col = lane & 15;
  int gbase = ks * 33;
  int nIter = 33 - ks;  // tiles 0..32 | 33..64

  if (t < 8) { Zro[t] = (f16)0; Ones[t] = (f16)1; }
  {
    float vm = (t < 65) ? kmaxp[bh * 65 + t] : 0.f;
#pragma unroll
    for (int d = 1; d < 64; d <<= 1) vm = fmaxf(vm, __shfl_xor(vm, d));
    if (lane == 0) red8[wid] = vm;
  }

  const f16* khb = k_h + ((size_t)bh * 4160 + gbase * 64) * 40;
  const f16* vtb = vt_h + (size_t)bh * 40 * 4160;

  // Staging decomposition over 512 threads: 640 uint4 per tile-pair.
  //   r0: t<320 -> K[t]; t>=320 -> V[j=t-320] (row=j>>3, seg=j&7)
  //   r1: t<128 -> V[j=192+t]
  uint4 r0, r1 = {0, 0, 0, 0};
  {
    int k00 = gbase << 6;
    if (t < 320) {
      r0 = *(const uint4*)(khb + t * 8);
    } else {
      int j = t - 320;
      r0 = *(const uint4*)(vtb + (size_t)(j >> 3) * 4160 + k00 + (j & 7) * 8);
    }
    if (t < 128) {
      int j = 192 + t;
      r1 = *(const uint4*)(vtb + (size_t)(j >> 3) * 4160 + k00 + (j & 7) * 8);
    }
  }

  half8 zero8;
#pragma unroll
  for (int j = 0; j < 8; ++j) zero8[j] = (f16)0;

  // Q direct global->reg (q pre-scaled by c1l in K1b); 16 q rows per wave.
  half8 bq0, bq1, q32v;
  {
    const f16* qr = q_h + ((size_t)bh * 4097 + qbase + wid * 16 + col) * 40;
    bq0 = *(const half8*)(qr + quad * 8);
    q32v = *(const half8*)(qr + 32);  // dims 32..39 (same row for all quads)
  }
  __syncthreads();

  float mk = fmaxf(fmaxf(fmaxf(red8[0], red8[1]), fmaxf(red8[2], red8[3])),
                   fmaxf(fmaxf(red8[4], red8[5]), fmaxf(red8[6], red8[7])));

  {
    float s = 0.f;
#pragma unroll
    for (int j = 0; j < 8; ++j) {
      float a0 = (float)bq0[j];
      s += a0 * a0;
    }
    s += __shfl_xor(s, 16);   // sum dims 0..31 across quads
    s += __shfl_xor(s, 32);
#pragma unroll
    for (int j = 0; j < 8; ++j) {
      float a1 = (float)q32v[j];
      s += a1 * a1;           // dims 32..39 (uniform across quads)
    }
    float mfl = sqrtf(s * mk) - 14.0f;  // Delta=14 anti-subnormal boost
    half8 e = zero8;
    e[0] = (f16)(-mfl);
    // B-frag, second MFMA: quad0 = q dims 32..39; quad1 = {-mfl,0..} (pairs k40=1); else 0
    bq1 = (quad == 0) ? q32v : ((quad == 1) ? e : zero8);
  }

  f32x4 o_[3];
#pragma unroll
  for (int nv = 0; nv < 3; ++nv)
#pragma unroll
    for (int r = 0; r < 4; ++r) o_[nv][r] = 0.f;

  for (int kt = 0; kt < nIter; ++kt) {
    int bsel = kt & 1;
    int g = gbase + kt;
    if (t < 320) {
      *(uint4*)(&Ks[bsel][t * 8]) = r0;
    } else {
      int j = t - 320;
      *(uint4*)(&Vs[bsel][(j >> 3) * 72 + (j & 7) * 8]) = r0;
    }
    if (t < 128) {
      int j = 192 + t;
      *(uint4*)(&Vs[bsel][(j >> 3) * 72 + (j & 7) * 8]) = r1;
    }
    if (kt + 1 < nIter) {
      const f16* kn = khb + (size_t)(kt + 1) * 2560;
      int k0n = (g + 1) << 6;
      if (t < 320) {
        r0 = *(const uint4*)(kn + t * 8);
      } else {
        int j = t - 320;
        r0 = *(const uint4*)(vtb + (size_t)(j >> 3) * 4160 + k0n + (j & 7) * 8);
      }
      if (t < 128) {
        int j = 192 + t;
        r1 = *(const uint4*)(vtb + (size_t)(j >> 3) * 4160 + k0n + (j & 7) * 8);
      }
    }
    __syncthreads();

    bool lastt = (g == 64);  // wave-uniform, true once (ks==1 final iter)

    // ---- phase A: QK^T (4 mt x 2 chained = 8 MFMAs) ----
    f32x4 acc[4];
#pragma unroll
    for (int mt = 0; mt < 4; ++mt) {
      int row = mt * 16 + col;
      half8 ak0 = *(half8*)(&Ks[bsel][row * 40 + quad * 8]);
      const f16* pa1 = (quad == 0) ? &Ks[bsel][row * 40 + 32]
                                   : ((quad == 1) ? Ones : Zro);
      half8 ak1 = *(half8*)pa1;
      f32x4 a; a[0] = 0.f; a[1] = 0.f; a[2] = 0.f; a[3] = 0.f;
      a = MFMA16(ak0, bq0, a);
      a = MFMA16(ak1, bq1, a);
      acc[mt] = a;
    }

    // ---- phase B: exp2 + pack + cross-quad redistribute ----
    half8 pa[2];
#pragma unroll
    for (int kk2 = 0; kk2 < 2; ++kk2) {
      float p0[4], p1[4];
#pragma unroll
      for (int r = 0; r < 4; ++r) {
        p0[r] = __builtin_amdgcn_exp2f(acc[kk2 * 2][r]);
        p1[r] = __builtin_amdgcn_exp2f(acc[kk2 * 2 + 1][r]);
      }
      if (__builtin_expect(lastt, 0)) {  // poison rows: keep only k-elem 0 (s=4096)
#pragma unroll
        for (int r = 0; r < 4; ++r) {
          p0[r] = (kk2 == 0 && (quad * 4 + r) == 0) ? p0[r] : 0.f;
          p1[r] = 0.f;
        }
      }
      unsigned sr[4];
      sr[0] = pk2(p0[0], p0[1]);
      sr[1] = pk2(p0[2], p0[3]);
      sr[2] = pk2(p1[0], p1[1]);
      sr[3] = pk2(p1[2], p1[3]);
      plswap_pair(sr[0], sr[2]);  // -> frag regs 0 and 2
      plswap_pair(sr[1], sr[3]);  // -> frag regs 1 and 3
      u32x4 uu; uu[0] = sr[0]; uu[1] = sr[1]; uu[2] = sr[2]; uu[3] = sr[3];
      pa[kk2] = __builtin_bit_cast(half8, uu);
    }

    // ---- phase C: PV (6 MFMAs) ----
#pragma unroll
    for (int kk2 = 0; kk2 < 2; ++kk2)
#pragma unroll
      for (int nv = 0; nv < 3; ++nv) {
        int d = nv * 16 + col;
        const f16* vp = (d < 40) ? &Vs[bsel][d * 72 + kk2 * 32 + quad * 8]
                                 : ((d == 40) ? Ones : Zro);
        half8 bv = *(half8*)vp;
        o_[nv] = MFMA16(pa[kk2], bv, o_[nv]);
      }
  }

  float* pb = pacc + (size_t)(ks * 16 + bh) * 4096 * 48;
#pragma unroll
  for (int nv = 0; nv < 3; ++nv)
#pragma unroll
    for (int r = 0; r < 4; ++r) {
      int q = qbase + wid * 16 + quad * 4 + r;
      pb[(size_t)q * 48 + nv * 16 + col] = o_[nv][r];
    }
}

// ---------------- K3: combine K-split partials + LayerNorm + residual + upsample --------
__global__ __launch_bounds__(256) void k_ln_out(
    const float* __restrict__ pacc, const float* __restrict__ lnw,
    const float* __restrict__ lnb, float* __restrict__ out) {
  __shared__ float g[16 * 164];
  __shared__ float linv[16 * 4];
  int y = blockIdx.x, b = blockIdx.y, z = blockIdx.z, t = threadIdx.x;
  const size_t P1 = (size_t)16 * 4096 * 48;
  int w0 = z * 16;
  if (t < 64) {
    int row = t >> 2, h = t & 3;
    size_t i0 = ((size_t)(b * 4 + h) * 4096 + y * 64 + w0 + row) * 48 + 40;
    linv[row * 4 + h] = 1.f / (pacc[i0] + pacc[P1 + i0]);
  }
  __syncthreads();
#pragma unroll
  for (int it = 0; it < 3; ++it) {
    int flat = t + it * 256;  // [0,640) f32x4 units
    if (flat < 640) {
      int row = flat / 40, dq = flat - row * 40;
      int h = dq / 10, d = (dq - h * 10) * 4;
      size_t idx = ((size_t)(b * 4 + h) * 4096 + y * 64 + w0 + row) * 48 + d;
      f32x4 v0 = *(const f32x4*)(pacc + idx);
      f32x4 v1 = *(const f32x4*)(pacc + P1 + idx);
      float li = linv[row * 4 + h];
      f32x4 gv;
#pragma unroll
      for (int j = 0; j < 4; ++j) gv[j] = (v0[j] + v1[j]) * li;
      *(f32x4*)(g + row * 164 + h * 40 + d) = gv;
    }
  }
  __syncthreads();
  int row = t >> 4, part = t & 15;  // 16 rows x 16 parts x 10 cols
  float* gr = g + row * 164 + part * 10;
  float s1 = 0.f, s2 = 0.f;
#pragma unroll
  for (int j = 0; j < 10; ++j) { float v = gr[j]; s1 += v; s2 += v * v; }
  s1 += __shfl_xor(s1, 1); s1 += __shfl_xor(s1, 2);
  s1 += __shfl_xor(s1, 4); s1 += __shfl_xor(s1, 8);
  s2 += __shfl_xor(s2, 1); s2 += __shfl_xor(s2, 2);
  s2 += __shfl_xor(s2, 4); s2 += __shfl_xor(s2, 8);
  float mu = s1 * (1.f / 160.f);
  float var = s2 * (1.f / 160.f) - mu * mu;
  float inv = rsqrtf(var + 1e-5f);
  const float* lw = lnw + part * 10;
  const float* lb = lnb + part * 10;
#pragma unroll
  for (int j = 0; j < 10; ++j) {
    float v = gr[j];
    gr[j] = (v - mu) * inv * lw[j] + lb[j] + v;
  }
  __syncthreads();
  int Yo = t >> 7, rem = t & 127, xp = rem & 31, cpar = rem >> 5;
  int rl = xp >> 1;
  float* ob = out + (2 * y + Yo) * 128 + z * 32 + xp;
  for (int c = cpar; c < 160; c += 4)
    ob[(size_t)(b * 160 + c) * 16384] = g[rl * 164 + c];
}

extern "C" void kernel_launch(void* const* d_in, const int* in_sizes, int n_in,
                              void* d_out, int out_size, void* d_ws, size_t ws_size,
                              hipStream_t stream) {
  const float* x   = (const float*)d_in[0];
  const float* w1  = (const float*)d_in[1];
  const float* b1  = (const float*)d_in[2];
  const float* w2  = (const float*)d_in[3];
  const float* b2  = (const float*)d_in[4];
  const float* pe  = (const float*)d_in[5];
  const float* wq  = (const float*)d_in[6];
  const float* wk  = (const float*)d_in[7];
  const float* wvp = (const float*)d_in[8];
  const float* lnw = (const float*)d_in[9];
  const float* lnb = (const float*)d_in[10];
  float* out = (float*)d_out;

  char* p = (char*)d_ws;
  f16* q_h   = (f16*)p;   p += (size_t)16 * 4097 * 40 * 2;       // 5,244,160
  f16* k_h   = (f16*)p;   p += (size_t)16 * 4160 * 40 * 2;       // 5,324,800
  f16* vt_h  = (f16*)p;   p += (size_t)16 * 40 * 4160 * 2;       // 5,324,800
  float* pacc = (float*)p; p += (size_t)2 * 16 * 4096 * 48 * 4;  // 25,165,824
  float* kmaxp = (float*)p; p += 16 * 65 * 4;                    // 4,160
  f16* fh    = (f16*)p;   p += (size_t)4 * 4096 * 160 * 2;       // 5,242,880
  f16* wf    = (f16*)p;   p += (size_t)3 * 160 * 160 * 2;        // 153,600
  // total ~46.5 MB

  k_prep<<<dim3(25, 3), 256, 0, stream>>>(wq, wk, wvp, wf);
  k_conv<<<dim3(64, 4), 256, 0, stream>>>(x, w1, b1, w2, b2, pe, wq, wk, wvp,
                                          fh, q_h, k_h, vt_h, kmaxp);
  k_qkv<<<dim3(64, 4, 3), 256, 0, stream>>>(fh, wf, q_h, k_h, vt_h);
  k_sq<<<dim3(16, 16), 256, 0, stream>>>(k_h, kmaxp);
  k_attn<<<dim3(32, 16, 2), 512, 0, stream>>>(q_h, k_h, vt_h, kmaxp, pacc);
  k_ln_out<<<dim3(64, 4, 4), 256, 0, stream>>>(pacc, lnw, lnb, out);
}

// Round 7
// 209.620 us; speedup vs baseline: 1.0080x; 1.0080x over previous
//
#include <hip/hip_runtime.h>

typedef _Float16 f16;
typedef _Float16 half2v __attribute__((ext_vector_type(2)));
typedef _Float16 half4v __attribute__((ext_vector_type(4)));
typedef _Float16 half8 __attribute__((ext_vector_type(8)));
typedef float f32x4 __attribute__((ext_vector_type(4)));
typedef unsigned u32x4 __attribute__((ext_vector_type(4)));

#define MFMA16(a, b, c) __builtin_amdgcn_mfma_f32_16x16x32_f16((a), (b), (c), 0, 0, 0)

__device__ __forceinline__ unsigned pk2(float a, float b) {
  return __builtin_bit_cast(unsigned, __builtin_amdgcn_cvt_pkrtz(a, b));
}

// Cross-quad redistribution for P (QK^T C-layout -> PV A-layout):
//   permlane32_swap: vdst.{q2,q3} <-> vsrc.{q0,q1}
//   permlane16_swap: vdst.{q1,q3} <-> vsrc.{q0,q2}
__device__ __forceinline__ void plswap_pair(unsigned& a, unsigned& b) {
  asm("s_nop 1\n\t"
      "v_permlane32_swap_b32 %0, %1\n\t"
      "v_permlane16_swap_b32 %0, %1"
      : "+v"(a), "+v"(b));
}

// Sizes: B=4, CI=64, H=W=128 ; conv out 64x64 ; C=160 ; S=4097 ; SQ=4096 ; NH=4 ; HD=40
// Budget (R15/R16 findings): harness fill ~45us fixed; k_attn 75us (R13 4-wave form is
// the balance point: R16's 8x16q doubled LDS traffic per useful MFMA -> 91us, reverted);
// aux+gaps ~81us, largest = k_conv at 1 block/CU.
// R17: k_conv occupancy x2: weights pre-converted to global f16 (k_prep now flat over
// wq/wk/wv/w1/w2), no weight staging/barrier, LDS 112KB -> 33KB, and 32-pos tiles:
// grid (128,4) = 512 blocks = 2 blocks/CU, 8 waves/CU.

// ---------------- K0: convert all weights f32 -> f16 ------------------------------------
// wf layout (f16): [0) wq 25600 | [25600) wk 25600 | [51200) wv 25600 |
//                  [76800) w1 64x256 | [93184) w2 160x64 | total 103424
__global__ __launch_bounds__(256) void k_prep(
    const float* __restrict__ wq, const float* __restrict__ wk,
    const float* __restrict__ wv, const float* __restrict__ w1,
    const float* __restrict__ w2, f16* __restrict__ wf) {
  int i4 = blockIdx.x * 256 + threadIdx.x;  // [0,25856) f32x4 units
  const float* src;
  int idx;
  if (i4 < 19200) { src = (i4 < 6400) ? wq : (i4 < 12800 ? wk : wv); idx = i4 % 6400; }
  else if (i4 < 23296) { src = w1; idx = i4 - 19200; }
  else { src = w2; idx = i4 - 23296; }
  f32x4 v = *(const f32x4*)(src + idx * 4);
  uint2 u = {pk2(v[0], v[1]), pk2(v[2], v[3])};
  *(uint2*)(wf + i4 * 4) = u;
}

// ---------------- K1: conv1(MFMA) -> conv2(MFMA)+leaky+pe -> fh + pad row ---------------
// grid (128 yt, 4 b) = 512 blocks -> 2 blocks/CU. 32-pos tiles: yt -> row i = yt/2,
// col half j0 = (yt&1)*32. Weights direct from global f16 (L2-hot), no staging barriers.
__global__ __launch_bounds__(256) void k_conv(
    const float* __restrict__ x, const f16* __restrict__ wf,
    const float* __restrict__ b1, const float* __restrict__ b2,
    const float* __restrict__ pe,
    const float* __restrict__ wq, const float* __restrict__ wk, const float* __restrict__ wv,
    f16* __restrict__ fh, f16* __restrict__ q_h, f16* __restrict__ k_h,
    f16* __restrict__ vt_h, float* __restrict__ kmaxp) {
  // LDS: xh [0,16896) 32x264 f16 ; fT [16896,27648) 32x168 f16 ;
  //      c1t [27648,32256) 32x72 f16 ; red160 [32256,32896) 160 f32.  ~33KB.
  __shared__ __attribute__((aligned(16))) char smem[32896];
  f16* xh   = (f16*)smem;
  f16* fT   = (f16*)(smem + 16896);
  f16* c1t  = (f16*)(smem + 27648);
  float* red160 = (float*)(smem + 32256);

  const f16* w1f = wf + 76800;
  const f16* w2f = wf + 93184;
  const float c1l = 0.15811388300841898f * 1.4426950408889634f;  // scale*log2e

  int yt = blockIdx.x, b = blockIdx.y;
  int i = yt >> 1, j0 = (yt & 1) * 32;
  int pbase = i * 64 + j0;  // 32 consecutive global positions
  int t = threadIdx.x, lane = t & 63, wv4 = t >> 6, quad = lane >> 4, col = lane & 15;

  // ---- phase 1: stage xh (f32->f16, B layout) ----
#pragma unroll
  for (int it = 0; it < 16; ++it) {
    int flat = t + it * 256;  // [0,4096) float2 units
    int pos = flat & 31, r = (flat >> 5) & 1, ci = flat >> 6;
    float2 v = *(const float2*)(x + (size_t)(b * 64 + ci) * 16384 +
                                (2 * i + r) * 128 + 2 * (j0 + pos));
    *(unsigned*)(xh + pos * 264 + ci * 4 + r * 2) = pk2(v.x, v.y);
  }
  __syncthreads();

  // ---- phase 2: conv1 MFMA  c1[co][pos] = w1f[co][.] . xh[pos][.] + b1 ----
  float b1v[4];
#pragma unroll
  for (int r = 0; r < 4; ++r) b1v[r] = b1[wv4 * 16 + quad * 4 + r];
  f32x4 acc1[2];
#pragma unroll
  for (int nt = 0; nt < 2; ++nt)
#pragma unroll
    for (int r = 0; r < 4; ++r) acc1[nt][r] = b1v[r];
#pragma unroll
  for (int kk = 0; kk < 8; ++kk) {
    half8 a = *(const half8*)(w1f + (wv4 * 16 + col) * 256 + kk * 32 + quad * 8);
#pragma unroll
    for (int nt = 0; nt < 2; ++nt) {
      half8 bfr = *(half8*)(xh + (nt * 16 + col) * 264 + kk * 32 + quad * 8);
      acc1[nt] = MFMA16(a, bfr, acc1[nt]);
    }
  }
#pragma unroll
  for (int nt = 0; nt < 2; ++nt) {
    uint2 u = {pk2(acc1[nt][0], acc1[nt][1]), pk2(acc1[nt][2], acc1[nt][3])};
    *(uint2*)(c1t + (nt * 16 + col) * 72 + wv4 * 16 + quad * 4) = u;
  }
  __syncthreads();

  // ---- phase 3: conv2 MFMA. wave wv4: pos group pg = wv4&1, c2 half ch = wv4>>1 ----
  int pg = wv4 & 1, ch = wv4 >> 1;
  f32x4 acc2[5];
#pragma unroll
  for (int mt = 0; mt < 5; ++mt)
#pragma unroll
    for (int r = 0; r < 4; ++r) acc2[mt][r] = b2[ch * 80 + mt * 16 + quad * 4 + r];
  half8 bb0 = *(half8*)(c1t + (pg * 16 + col) * 72 + quad * 8);
  half8 bb1 = *(half8*)(c1t + (pg * 16 + col) * 72 + 32 + quad * 8);
#pragma unroll
  for (int mt = 0; mt < 5; ++mt) {
    half8 a0 = *(const half8*)(w2f + (ch * 80 + mt * 16 + col) * 64 + quad * 8);
    half8 a1 = *(const half8*)(w2f + (ch * 80 + mt * 16 + col) * 64 + 32 + quad * 8);
    acc2[mt] = MFMA16(a0, bb0, acc2[mt]);
    acc2[mt] = MFMA16(a1, bb1, acc2[mt]);
  }
  float pes = pe[pbase + pg * 16 + col];
#pragma unroll
  for (int mt = 0; mt < 5; ++mt) {
    float p[4];
#pragma unroll
    for (int r = 0; r < 4; ++r) {
      float v = acc2[mt][r];
      v = (v >= 0.f) ? v : 0.01f * v;  // leaky BEFORE pe add
      p[r] = v + pes;
    }
    uint2 u = {pk2(p[0], p[1]), pk2(p[2], p[3])};
    *(uint2*)(fT + (pg * 16 + col) * 168 + ch * 80 + mt * 16 + quad * 4) = u;
  }
  __syncthreads();

  // ---- phase 4: write fh[b][s][160] f16 (coalesced uint4) ----
#pragma unroll
  for (int it = 0; it < 3; ++it) {
    int flat = t + it * 256;  // [0,640)
    if (flat < 640) {
      int row = flat / 20, seg = flat - row * 20;
      *(uint4*)(fh + ((size_t)b * 4096 + pbase + row) * 160 + seg * 8) =
          *(const uint4*)(fT + row * 168 + seg * 8);
    }
  }

  // ---- pad row s=4096: f[4096][c] = pe[4096] for all c => qkv = pe4096 * rowsum(W) ----
  if (yt == 127) {
    float pe4 = pe[4096];
    if (t < 160) {
      int hh = t / 40, d = t - hh * 40, bh = b * 4 + hh;
#pragma unroll
      for (int kind = 0; kind < 3; ++kind) {
        const float* wsp = (kind == 0) ? wq : (kind == 1 ? wk : wv);
        const float* wr = wsp + t * 160;
        float rs = 0.f;
#pragma unroll
        for (int c4 = 0; c4 < 40; ++c4) {
          f32x4 v = *(const f32x4*)(wr + c4 * 4);
          rs += v[0] + v[1] + v[2] + v[3];
        }
        float val = pe4 * rs;
        if (kind == 0)      q_h[((size_t)bh * 4097 + 4096) * 40 + d] = (f16)(val * c1l);
        else if (kind == 1) { k_h[((size_t)bh * 4160 + 4096) * 40 + d] = (f16)val;
                              red160[t] = val * val; }
        else                vt_h[((size_t)bh * 40 + d) * 4160 + 4096] = (f16)val;
      }
    }
    __syncthreads();
    if (t < 4) {
      float s = 0.f;
#pragma unroll
      for (int j = 0; j < 40; ++j) s += red160[t * 40 + j];
      kmaxp[(b * 4 + t) * 65 + 64] = s;
    }
  }
}

// ---------------- K1b: QKV GEMM, both operands direct from global f16 -------------------
__global__ __launch_bounds__(256) void k_qkv(
    const f16* __restrict__ fh, const f16* __restrict__ wf,
    f16* __restrict__ q_h, f16* __restrict__ k_h, f16* __restrict__ vt_h) {
  __shared__ __attribute__((aligned(16))) f16 Lv[160 * 72];
  int y = blockIdx.x, b = blockIdx.y, kind = blockIdx.z;
  int t = threadIdx.x, lane = t & 63, wvv = t >> 6, quad = lane >> 4, col = lane & 15;
  int s0 = y * 64;
  const float c1l = 0.15811388300841898f * 1.4426950408889634f;  // scale*log2e
  const f16* wk_ = wf + (size_t)kind * 25600;

  half8 af[5];
  int rowA = wvv * 16 + col;
#pragma unroll
  for (int kk = 0; kk < 5; ++kk)
    af[kk] = *(const half8*)(fh + ((size_t)b * 4096 + s0 + rowA) * 160 + kk * 32 + quad * 8);

#pragma unroll
  for (int n0 = 0; n0 < 10; ++n0) {
    f32x4 acc; acc[0] = 0.f; acc[1] = 0.f; acc[2] = 0.f; acc[3] = 0.f;
    int rowB = n0 * 16 + col;
#pragma unroll
    for (int kk = 0; kk < 5; ++kk) {
      half8 bf = *(const half8*)(wk_ + rowB * 160 + kk * 32 + quad * 8);
      acc = MFMA16(af[kk], bf, acc);
    }
    int o = n0 * 16 + col;
    int hh = o / 40, d = o - hh * 40;
    int bh = b * 4 + hh;
    if (kind == 2) {
      half4v hv;
#pragma unroll
      for (int r = 0; r < 4; ++r) hv[r] = (f16)acc[r];
      *(half4v*)(Lv + o * 72 + wvv * 16 + quad * 4) = hv;
    } else {
#pragma unroll
      for (int r = 0; r < 4; ++r) {
        int s = s0 + wvv * 16 + quad * 4 + r;  // <= 4095
        if (kind == 0) q_h[((size_t)bh * 4097 + s) * 40 + d] = (f16)(acc[r] * c1l);
        else           k_h[((size_t)bh * 4160 + s) * 40 + d] = (f16)acc[r];
      }
    }
  }
  if (kind == 2) {
    __syncthreads();
#pragma unroll
    for (int it = 0; it < 5; ++it) {
      int c = t + it * 256;  // [0,1280): 160 rows x 8 uint4 segs
      int row = c >> 3, seg = c & 7;
      int hh = row / 40, d = row - hh * 40;
      *(uint4*)(vt_h + ((size_t)(b * 4 + hh) * 40 + d) * 4160 + s0 + seg * 8) =
          *(const uint4*)(Lv + row * 72 + seg * 8);
    }
  }
}

// ---------------- K1c: kmaxp slots 0..63 from k_h ---------------------------------------
__global__ __launch_bounds__(256) void k_sq(
    const f16* __restrict__ k_h, float* __restrict__ kmaxp) {
  int t = threadIdx.x, lane = t & 63, wvv = t >> 6;
  int slot = blockIdx.x * 4 + wvv;  // 0..63
  int bh = blockIdx.y;
  int s = slot * 64 + lane;
  const f16* kr = k_h + ((size_t)bh * 4160 + s) * 40;
  float sum = 0.f;
#pragma unroll
  for (int i = 0; i < 5; ++i) {
    half8 v = *(const half8*)(kr + i * 8);
#pragma unroll
    for (int j = 0; j < 8; ++j) { float xv = (float)v[j]; sum += xv * xv; }
  }
#pragma unroll
  for (int d = 1; d < 64; d <<= 1) sum = fmaxf(sum, __shfl_xor(sum, d));
  if (lane == 0) kmaxp[bh * 65 + slot] = sum;
}

// ---------------- K2: flash attention, K-split x2, packed d40, K+V LDS dbuf -------------
// grid (32 qt, 16 bh, 2 ks) = 1024 blocks -> 4 blocks/CU. R13-proven form (74.9 us):
// 4 waves x 32 q; full phases: 8 QK MFMA -> exp2/pack/permlane burst -> 12 PV MFMA.
__global__ __launch_bounds__(256, 4) void k_attn(
    const f16* __restrict__ q_h, const f16* __restrict__ k_h,
    const f16* __restrict__ vt_h, const float* __restrict__ kmaxp,
    float* __restrict__ pacc) {
  __shared__ __attribute__((aligned(16))) f16 Ks[2][64 * 40];
  __shared__ __attribute__((aligned(16))) f16 Vs[2][40 * 72];
  __shared__ __attribute__((aligned(16))) f16 Ones[8];
  __shared__ __attribute__((aligned(16))) f16 Zro[8];
  __shared__ __attribute__((aligned(16))) float red4[4];

  int qt = blockIdx.x, bh = blockIdx.y, ks = blockIdx.z;
  int qbase = qt * 128;
  int t = threadIdx.x, lane = t & 63, wv = t >> 6, quad = lane >> 4, col = lane & 15;
  int gbase = ks * 33;
  int nIter = 33 - ks;  // tiles 0..32 | 33..64

  if (t < 8) { Zro[t] = (f16)0; Ones[t] = (f16)1; }
  {
    float vm = (t < 65) ? kmaxp[bh * 65 + t] : 0.f;
#pragma unroll
    for (int d = 1; d < 64; d <<= 1) vm = fmaxf(vm, __shfl_xor(vm, d));
    if (lane == 0) red4[wv] = vm;
  }

  const f16* khb = k_h + ((size_t)bh * 4160 + gbase * 64) * 40;
  const f16* vtb = vt_h + (size_t)bh * 40 * 4160;
  int vrow = t >> 3, vseg = t & 7;
  uint4 rka = *(const uint4*)(khb + t * 8);
  uint4 rkb = {0, 0, 0, 0}, rvb = {0, 0, 0, 0};
  if (t < 64) rkb = *(const uint4*)(khb + (256 + t) * 8);
  uint4 rva = *(const uint4*)(vtb + vrow * 4160 + gbase * 64 + vseg * 8);
  if (t < 64) rvb = *(const uint4*)(vtb + (32 + vrow) * 4160 + gbase * 64 + vseg * 8);

  half8 zero8;
#pragma unroll
  for (int j = 0; j < 8; ++j) zero8[j] = (f16)0;

  // Q direct global->reg (q pre-scaled by c1l in K1b)
  half8 bq[2][2], q32[2];
#pragma unroll
  for (int nt = 0; nt < 2; ++nt) {
    const f16* qr = q_h + ((size_t)bh * 4097 + qbase + wv * 32 + nt * 16 + col) * 40;
    bq[nt][0] = *(const half8*)(qr + quad * 8);
    q32[nt] = *(const half8*)(qr + 32);  // dims 32..39 (same row for all quads)
  }
  __syncthreads();

  float mk = fmaxf(fmaxf(red4[0], red4[1]), fmaxf(red4[2], red4[3]));

#pragma unroll
  for (int nt = 0; nt < 2; ++nt) {
    float s = 0.f;
#pragma unroll
    for (int j = 0; j < 8; ++j) {
      float a0 = (float)bq[nt][0][j];
      s += a0 * a0;
    }
    s += __shfl_xor(s, 16);   // sum dims 0..31 across quads
    s += __shfl_xor(s, 32);
#pragma unroll
    for (int j = 0; j < 8; ++j) {
      float a1 = (float)q32[nt][j];
      s += a1 * a1;           // dims 32..39 (uniform across quads)
    }
    float mfl = sqrtf(s * mk) - 14.0f;  // Delta=14 anti-subnormal boost
    half8 e = zero8;
    e[0] = (f16)(-mfl);
    // B-frag, second MFMA: quad0 = q dims 32..39; quad1 = {-mfl,0..} (pairs k40=1); else 0
    bq[nt][1] = (quad == 0) ? q32[nt] : ((quad == 1) ? e : zero8);
  }

  f32x4 o_[2][3];
#pragma unroll
  for (int a = 0; a < 2; ++a)
#pragma unroll
    for (int b2 = 0; b2 < 3; ++b2)
#pragma unroll
      for (int r = 0; r < 4; ++r) o_[a][b2][r] = 0.f;

  for (int kt = 0; kt < nIter; ++kt) {
    int bsel = kt & 1;
    int g = gbase + kt;
    *(uint4*)(&Ks[bsel][t * 8]) = rka;
    if (t < 64) *(uint4*)(&Ks[bsel][(256 + t) * 8]) = rkb;
    *(uint4*)(&Vs[bsel][vrow * 72 + vseg * 8]) = rva;
    if (t < 64) *(uint4*)(&Vs[bsel][(32 + vrow) * 72 + vseg * 8]) = rvb;
    if (kt + 1 < nIter) {
      const f16* kn = khb + (size_t)(kt + 1) * 2560;
      int k0n = (g + 1) << 6;
      rka = *(const uint4*)(kn + t * 8);
      if (t < 64) rkb = *(const uint4*)(kn + (256 + t) * 8);
      rva = *(const uint4*)(vtb + vrow * 4160 + k0n + vseg * 8);
      if (t < 64) rvb = *(const uint4*)(vtb + (32 + vrow) * 4160 + k0n + vseg * 8);
    }
    __syncthreads();

    bool lastt = (g == 64);  // wave-uniform, true once (ks==1 final iter)

    // ---- phase A: all QK^T (8 independent MFMAs) ----
    f32x4 acc[4][2];  // [mt][nt]
#pragma unroll
    for (int mt = 0; mt < 4; ++mt) {
      int row = mt * 16 + col;
      half8 ak0 = *(half8*)(&Ks[bsel][row * 40 + quad * 8]);
      const f16* pa1 = (quad == 0) ? &Ks[bsel][row * 40 + 32]
                                   : ((quad == 1) ? Ones : Zro);
      half8 ak1 = *(half8*)pa1;
#pragma unroll
      for (int nt = 0; nt < 2; ++nt) {
        f32x4 a; a[0] = 0.f; a[1] = 0.f; a[2] = 0.f; a[3] = 0.f;
        a = MFMA16(ak0, bq[nt][0], a);
        a = MFMA16(ak1, bq[nt][1], a);
        acc[mt][nt] = a;
      }
    }

    // ---- phase B: exp2 + pack + cross-quad redistribute (one VALU burst) ----
    half8 pa[2][2];  // [kk2][nt]
#pragma unroll
    for (int kk2 = 0; kk2 < 2; ++kk2)
#pragma unroll
      for (int nt = 0; nt < 2; ++nt) {
        float p0[4], p1[4];
#pragma unroll
        for (int r = 0; r < 4; ++r) {
          p0[r] = __builtin_amdgcn_exp2f(acc[kk2 * 2][nt][r]);
          p1[r] = __builtin_amdgcn_exp2f(acc[kk2 * 2 + 1][nt][r]);
        }
        if (__builtin_expect(lastt, 0)) {  // poison rows: keep only k-elem 0 (s=4096)
#pragma unroll
          for (int r = 0; r < 4; ++r) {
            p0[r] = (kk2 == 0 && (quad * 4 + r) == 0) ? p0[r] : 0.f;
            p1[r] = 0.f;
          }
        }
        unsigned sr[4];
        sr[0] = pk2(p0[0], p0[1]);
        sr[1] = pk2(p0[2], p0[3]);
        sr[2] = pk2(p1[0], p1[1]);
        sr[3] = pk2(p1[2], p1[3]);
        plswap_pair(sr[0], sr[2]);  // -> frag regs 0 and 2
        plswap_pair(sr[1], sr[3]);  // -> frag regs 1 and 3
        u32x4 uu; uu[0] = sr[0]; uu[1] = sr[1]; uu[2] = sr[2]; uu[3] = sr[3];
        pa[kk2][nt] = __builtin_bit_cast(half8, uu);
      }

    // ---- phase C: all PV (12 MFMAs) ----
#pragma unroll
    for (int kk2 = 0; kk2 < 2; ++kk2)
#pragma unroll
      for (int nv = 0; nv < 3; ++nv) {
        int d = nv * 16 + col;
        const f16* vp = (d < 40) ? &Vs[bsel][d * 72 + kk2 * 32 + quad * 8]
                                 : ((d == 40) ? Ones : Zro);
        half8 bv = *(half8*)vp;
        o_[0][nv] = MFMA16(pa[kk2][0], bv, o_[0][nv]);
        o_[1][nv] = MFMA16(pa[kk2][1], bv, o_[1][nv]);
      }
  }

  float* pb = pacc + (size_t)(ks * 16 + bh) * 4096 * 48;
#pragma unroll
  for (int mtq = 0; mtq < 2; ++mtq)
#pragma unroll
    for (int nv = 0; nv < 3; ++nv)
#pragma unroll
      for (int r = 0; r < 4; ++r) {
        int q = qbase + wv * 32 + mtq * 16 + quad * 4 + r;
        pb[(size_t)q * 48 + nv * 16 + col] = o_[mtq][nv][r];
      }
}

// ---------------- K3: combine K-split partials + LayerNorm + residual + upsample --------
__global__ __launch_bounds__(256) void k_ln_out(
    const float* __restrict__ pacc, const float* __restrict__ lnw,
    const float* __restrict__ lnb, float* __restrict__ out) {
  __shared__ float g[16 * 164];
  __shared__ float linv[16 * 4];
  int y = blockIdx.x, b = blockIdx.y, z = blockIdx.z, t = threadIdx.x;
  const size_t P1 = (size_t)16 * 4096 * 48;
  int w0 = z * 16;
  if (t < 64) {
    int row = t >> 2, h = t & 3;
    size_t i0 = ((size_t)(b * 4 + h) * 4096 + y * 64 + w0 + row) * 48 + 40;
    linv[row * 4 + h] = 1.f / (pacc[i0] + pacc[P1 + i0]);
  }
  __syncthreads();
#pragma unroll
  for (int it = 0; it < 3; ++it) {
    int flat = t + it * 256;  // [0,640) f32x4 units
    if (flat < 640) {
      int row = flat / 40, dq = flat - row * 40;
      int h = dq / 10, d = (dq - h * 10) * 4;
      size_t idx = ((size_t)(b * 4 + h) * 4096 + y * 64 + w0 + row) * 48 + d;
      f32x4 v0 = *(const f32x4*)(pacc + idx);
      f32x4 v1 = *(const f32x4*)(pacc + P1 + idx);
      float li = linv[row * 4 + h];
      f32x4 gv;
#pragma unroll
      for (int j = 0; j < 4; ++j) gv[j] = (v0[j] + v1[j]) * li;
      *(f32x4*)(g + row * 164 + h * 40 + d) = gv;
    }
  }
  __syncthreads();
  int row = t >> 4, part = t & 15;  // 16 rows x 16 parts x 10 cols
  float* gr = g + row * 164 + part * 10;
  float s1 = 0.f, s2 = 0.f;
#pragma unroll
  for (int j = 0; j < 10; ++j) { float v = gr[j]; s1 += v; s2 += v * v; }
  s1 += __shfl_xor(s1, 1); s1 += __shfl_xor(s1, 2);
  s1 += __shfl_xor(s1, 4); s1 += __shfl_xor(s1, 8);
  s2 += __shfl_xor(s2, 1); s2 += __shfl_xor(s2, 2);
  s2 += __shfl_xor(s2, 4); s2 += __shfl_xor(s2, 8);
  float mu = s1 * (1.f / 160.f);
  float var = s2 * (1.f / 160.f) - mu * mu;
  float inv = rsqrtf(var + 1e-5f);
  const float* lw = lnw + part * 10;
  const float* lb = lnb + part * 10;
#pragma unroll
  for (int j = 0; j < 10; ++j) {
    float v = gr[j];
    gr[j] = (v - mu) * inv * lw[j] + lb[j] + v;
  }
  __syncthreads();
  int Yo = t >> 7, rem = t & 127, xp = rem & 31, cpar = rem >> 5;
  int rl = xp >> 1;
  float* ob = out + (2 * y + Yo) * 128 + z * 32 + xp;
  for (int c = cpar; c < 160; c += 4)
    ob[(size_t)(b * 160 + c) * 16384] = g[rl * 164 + c];
}

extern "C" void kernel_launch(void* const* d_in, const int* in_sizes, int n_in,
                              void* d_out, int out_size, void* d_ws, size_t ws_size,
                              hipStream_t stream) {
  const float* x   = (const float*)d_in[0];
  const float* w1  = (const float*)d_in[1];
  const float* b1  = (const float*)d_in[2];
  const float* w2  = (const float*)d_in[3];
  const float* b2  = (const float*)d_in[4];
  const float* pe  = (const float*)d_in[5];
  const float* wq  = (const float*)d_in[6];
  const float* wk  = (const float*)d_in[7];
  const float* wvp = (const float*)d_in[8];
  const float* lnw = (const float*)d_in[9];
  const float* lnb = (const float*)d_in[10];
  float* out = (float*)d_out;

  char* p = (char*)d_ws;
  f16* q_h   = (f16*)p;   p += (size_t)16 * 4097 * 40 * 2;       // 5,244,160
  f16* k_h   = (f16*)p;   p += (size_t)16 * 4160 * 40 * 2;       // 5,324,800
  f16* vt_h  = (f16*)p;   p += (size_t)16 * 40 * 4160 * 2;       // 5,324,800
  float* pacc = (float*)p; p += (size_t)2 * 16 * 4096 * 48 * 4;  // 25,165,824
  float* kmaxp = (float*)p; p += 16 * 65 * 4;                    // 4,160
  f16* fh    = (f16*)p;   p += (size_t)4 * 4096 * 160 * 2;       // 5,242,880
  f16* wf    = (f16*)p;   p += (size_t)103424 * 2;               // 206,848
  // total ~46.6 MB

  k_prep<<<dim3(101), 256, 0, stream>>>(wq, wk, wvp, w1, w2, wf);
  k_conv<<<dim3(128, 4), 256, 0, stream>>>(x, wf, b1, b2, pe, wq, wk, wvp,
                                           fh, q_h, k_h, vt_h, kmaxp);
  k_qkv<<<dim3(64, 4, 3), 256, 0, stream>>>(fh, wf, q_h, k_h, vt_h);
  k_sq<<<dim3(16, 16), 256, 0, stream>>>(k_h, kmaxp);
  k_attn<<<dim3(32, 16, 2), 256, 0, stream>>>(q_h, k_h, vt_h, kmaxp, pacc);
  k_ln_out<<<dim3(64, 4, 4), 256, 0, stream>>>(pacc, lnw, lnb, out);
}

// Round 8
// 201.144 us; speedup vs baseline: 1.0505x; 1.0421x over previous
//
#include <hip/hip_runtime.h>

typedef _Float16 f16;
typedef _Float16 half2v __attribute__((ext_vector_type(2)));
typedef _Float16 half4v __attribute__((ext_vector_type(4)));
typedef _Float16 half8 __attribute__((ext_vector_type(8)));
typedef float f32x4 __attribute__((ext_vector_type(4)));
typedef unsigned u32x4 __attribute__((ext_vector_type(4)));

#define MFMA16(a, b, c) __builtin_amdgcn_mfma_f32_16x16x32_f16((a), (b), (c), 0, 0, 0)

__device__ __forceinline__ unsigned pk2(float a, float b) {
  return __builtin_bit_cast(unsigned, __builtin_amdgcn_cvt_pkrtz(a, b));
}

// Cross-quad redistribution for P (QK^T C-layout -> PV A-layout):
//   permlane32_swap: vdst.{q2,q3} <-> vsrc.{q0,q1}
//   permlane16_swap: vdst.{q1,q3} <-> vsrc.{q0,q2}
__device__ __forceinline__ void plswap_pair(unsigned& a, unsigned& b) {
  asm("s_nop 1\n\t"
      "v_permlane32_swap_b32 %0, %1\n\t"
      "v_permlane16_swap_b32 %0, %1"
      : "+v"(a), "+v"(b));
}

// Sizes: B=4, CI=64, H=W=128 ; conv out 64x64 ; C=160 ; S=4097 ; SQ=4096 ; NH=4 ; HD=40
// q layout: [bh(16)][s(4097)][40] f16 packed, PRE-SCALED by c1l = scale*log2e
// k layout: [bh(16)][s(4160)][40] f16 packed (rows 4097.. poison, masked on last tile)
// vt layout: [bh(16)][d(40)][4160] f16
// kmaxp: [bh(16)][65] f32 partial max ||k||^2 per block, slot 64 = ||k_4096||^2
// pacc: [ks(2)][bh(16)][q(4096)][48] f32 partial o; col 40 = partial l (ones-column trick)
// Softmax: P = exp2(q'.k - mfl), mfl = |q'|*maxK - 14 (Cauchy-Schwarz, Delta=14), folded
// into the QK MFMA via dead k-dim 40.
// Structure = R13 (best: 201.2us; 3 launches; R14/R17 aux restructures were 0/negative).
// Budget: harness ws-fill ~45us fixed (R15) + k_attn ~75 + aux/gaps ~81.
// R18 (k_attn only): (1) XCD-aware bijective block swizzle - bh = xcd*2+bit so each
// XCD's 128 resident blocks share 2 bh of K/V (1.33MB, L2-fits; was 4x duplicated
// FETCH); (2) prefetch addressing strength-reduced to incrementing pointers.

// ---------------- K1: conv1(MFMA) -> conv2(MFMA)+leaky+pe -> QKV(MFMA) + k-norm ---------
__global__ __launch_bounds__(256) void k_convqkv(
    const float* __restrict__ x, const float* __restrict__ w1, const float* __restrict__ b1,
    const float* __restrict__ w2, const float* __restrict__ b2, const float* __restrict__ pe,
    const float* __restrict__ wq, const float* __restrict__ wk, const float* __restrict__ wv,
    f16* __restrict__ q_h, f16* __restrict__ k_h, f16* __restrict__ vt_h,
    float* __restrict__ kmaxp) {
  // LDS map (112192 B, 1 block/CU):
  //   [0,21504)        fT   64x168 f16   (conv2 out = QKV input)
  //   [21504,55360)    xh   64x264 f16 [pos][ciq]   | QKV overlay: wT 80x168 + red(16 f32)
  //   [55360,89152)    w1h  64x264 f16 [co][ciq]    | post-conv1 overlay: c1t 64x72 [pos][co]
  //                                                  | phase-4 overlay: Lv 80x72 f16 (vt repack)
  //                                                  | + red160 (pad-row knorm) at +9216
  //   [89152,112192)   w2h 160x72 f16 [c2][co]
  __shared__ __attribute__((aligned(16))) char smem[112192];
  f16* fT   = (f16*)smem;
  f16* xh   = (f16*)(smem + 21504);
  f16* wT   = (f16*)(smem + 21504);
  float* red = (float*)(smem + 48384);
  f16* w1h  = (f16*)(smem + 55360);
  f16* c1t  = (f16*)(smem + 55360);
  f16* Lv   = (f16*)(smem + 55360);
  float* red160 = (float*)(smem + 64576);
  f16* w2h  = (f16*)(smem + 89152);

  const float c1l = 0.15811388300841898f * 1.4426950408889634f;  // scale*log2e

  int y = blockIdx.x, b = blockIdx.y;
  int t = threadIdx.x, lane = t & 63, wv4 = t >> 6, quad = lane >> 4, col = lane & 15;
  int s0 = y * 64;

  // ---- phase 1: stage xh (f32->f16, B layout), w1h, w2h ----
  const float* xb = x + (b * 64) * 16384 + (2 * y) * 128;
#pragma unroll
  for (int it = 0; it < 32; ++it) {
    int flat = t + it * 256;  // [0,8192) float2 units
    int pos = flat & 63, r = (flat >> 6) & 1, ci = flat >> 7;
    float2 v = *(const float2*)(xb + ci * 16384 + r * 128 + 2 * pos);
    *(unsigned*)(xh + pos * 264 + ci * 4 + r * 2) = pk2(v.x, v.y);
  }
#pragma unroll
  for (int it = 0; it < 16; ++it) {
    int i4 = t + it * 256;  // [0,4096) f32x4 units of w1 (64x256)
    int co = i4 >> 6, q4 = (i4 & 63) * 4;
    f32x4 v = *(const f32x4*)(w1 + co * 256 + q4);
    uint2 u = {pk2(v[0], v[1]), pk2(v[2], v[3])};
    *(uint2*)(w1h + co * 264 + q4) = u;
  }
#pragma unroll
  for (int it = 0; it < 10; ++it) {
    int i4 = t + it * 256;  // [0,2560) f32x4 units of w2 (160x64)
    int c2 = i4 >> 4, q4 = (i4 & 15) * 4;
    f32x4 v = *(const f32x4*)(w2 + c2 * 64 + q4);
    uint2 u = {pk2(v[0], v[1]), pk2(v[2], v[3])};
    *(uint2*)(w2h + c2 * 72 + q4) = u;
  }
  __syncthreads();

  // ---- phase 2: conv1 MFMA  c1[co][pos] = w1h[co][.] . xh[pos][.] + b1 ----
  float b1v[4];
#pragma unroll
  for (int r = 0; r < 4; ++r) b1v[r] = b1[wv4 * 16 + quad * 4 + r];
  f32x4 acc1[4];
#pragma unroll
  for (int nt = 0; nt < 4; ++nt)
#pragma unroll
    for (int r = 0; r < 4; ++r) acc1[nt][r] = b1v[r];
#pragma unroll
  for (int kk = 0; kk < 8; ++kk) {
    half8 a = *(half8*)(w1h + (wv4 * 16 + col) * 264 + kk * 32 + quad * 8);
#pragma unroll
    for (int nt = 0; nt < 4; ++nt) {
      half8 bfr = *(half8*)(xh + (nt * 16 + col) * 264 + kk * 32 + quad * 8);
      acc1[nt] = MFMA16(a, bfr, acc1[nt]);
    }
  }
  __syncthreads();  // all w1h reads done before c1t overlay
#pragma unroll
  for (int nt = 0; nt < 4; ++nt) {
    uint2 u = {pk2(acc1[nt][0], acc1[nt][1]), pk2(acc1[nt][2], acc1[nt][3])};
    *(uint2*)(c1t + (nt * 16 + col) * 72 + wv4 * 16 + quad * 4) = u;
  }
  __syncthreads();

  // ---- phase 3: conv2 MFMA  f[pos][c2] = leaky(w2h[c2][.] . c1t[pos][.] + b2) + pe ----
  f32x4 acc2[10];
#pragma unroll
  for (int mt = 0; mt < 10; ++mt)
#pragma unroll
    for (int r = 0; r < 4; ++r) acc2[mt][r] = b2[mt * 16 + quad * 4 + r];
  half8 bb0 = *(half8*)(c1t + (wv4 * 16 + col) * 72 + quad * 8);
  half8 bb1 = *(half8*)(c1t + (wv4 * 16 + col) * 72 + 32 + quad * 8);
#pragma unroll
  for (int mt = 0; mt < 10; ++mt) {
    half8 a0 = *(half8*)(w2h + (mt * 16 + col) * 72 + quad * 8);
    half8 a1 = *(half8*)(w2h + (mt * 16 + col) * 72 + 32 + quad * 8);
    acc2[mt] = MFMA16(a0, bb0, acc2[mt]);
    acc2[mt] = MFMA16(a1, bb1, acc2[mt]);
  }
  float pes = pe[s0 + wv4 * 16 + col];
#pragma unroll
  for (int mt = 0; mt < 10; ++mt) {
    float p[4];
#pragma unroll
    for (int r = 0; r < 4; ++r) {
      float v = acc2[mt][r];
      v = (v >= 0.f) ? v : 0.01f * v;  // leaky BEFORE pe add
      p[r] = v + pes;
    }
    uint2 u = {pk2(p[0], p[1]), pk2(p[2], p[3])};
    *(uint2*)(fT + (wv4 * 16 + col) * 168 + mt * 16 + quad * 4) = u;
  }
  __syncthreads();

  // ---- phase 4: QKV MFMA (weights f32->f16 during staging) + k-norm partials ----
  half8 af[5];
  int rowA = wv4 * 16 + col;
#pragma unroll
  for (int kk = 0; kk < 5; ++kk)
    af[kk] = *(half8*)(fT + rowA * 168 + kk * 32 + quad * 8);

  float ks0[4], ks1[4];
#pragma unroll
  for (int r = 0; r < 4; ++r) { ks0[r] = 0.f; ks1[r] = 0.f; }

  for (int kind = 0; kind < 3; ++kind) {
    const float* wsp = (kind == 0) ? wq : (kind == 1 ? wk : wv);
    for (int hf = 0; hf < 2; ++hf) {
      __syncthreads();
      for (int c = t; c < 1600; c += 256) {
        int row = c / 20, seg = c - row * 20;
        const float* src = wsp + (hf * 80 + row) * 160 + seg * 8;
        f32x4 va = *(const f32x4*)src;
        f32x4 vb = *(const f32x4*)(src + 4);
        uint4 u = {pk2(va[0], va[1]), pk2(va[2], va[3]), pk2(vb[0], vb[1]), pk2(vb[2], vb[3])};
        *(uint4*)(wT + row * 168 + seg * 8) = u;
      }
      __syncthreads();
#pragma unroll
      for (int n0 = 0; n0 < 5; ++n0) {
        f32x4 acc; acc[0] = 0.f; acc[1] = 0.f; acc[2] = 0.f; acc[3] = 0.f;
        int rowB = n0 * 16 + col;
#pragma unroll
        for (int kk = 0; kk < 5; ++kk) {
          half8 bf = *(half8*)(wT + rowB * 168 + kk * 32 + quad * 8);
          acc = MFMA16(af[kk], bf, acc);
        }
        int o = (hf * 5 + n0) * 16 + col;
        int hh = o / 40, d = o - hh * 40;
        int bh = b * 4 + hh;
        if (kind == 1) {
          bool kidx = (n0 * 16 + col) >= 40;
#pragma unroll
          for (int r = 0; r < 4; ++r) {
            float z = acc[r] * acc[r];
            ks0[r] += kidx ? 0.f : z;
            ks1[r] += kidx ? z : 0.f;
          }
        }
        if (kind == 2) {
          // vt repack via LDS: Lv[o_local][s_local], coalesced store after sync
          half4v hv;
#pragma unroll
          for (int r = 0; r < 4; ++r) hv[r] = (f16)acc[r];
          *(half4v*)(Lv + (n0 * 16 + col) * 72 + wv4 * 16 + quad * 4) = hv;
        } else {
#pragma unroll
          for (int r = 0; r < 4; ++r) {
            int s = s0 + wv4 * 16 + quad * 4 + r;  // <= 4095 always (y < 64)
            if (kind == 0)      q_h[((size_t)bh * 4097 + s) * 40 + d] = (f16)(acc[r] * c1l);
            else                k_h[((size_t)bh * 4160 + s) * 40 + d] = (f16)acc[r];
          }
        }
      }
      if (kind == 1) {
        float m0 = 0.f, m1 = 0.f;
#pragma unroll
        for (int r = 0; r < 4; ++r) {
          float v0 = ks0[r], v1 = ks1[r];
          v0 += __shfl_xor(v0, 1); v0 += __shfl_xor(v0, 2);
          v0 += __shfl_xor(v0, 4); v0 += __shfl_xor(v0, 8);
          v1 += __shfl_xor(v1, 1); v1 += __shfl_xor(v1, 2);
          v1 += __shfl_xor(v1, 4); v1 += __shfl_xor(v1, 8);
          m0 = fmaxf(m0, v0); m1 = fmaxf(m1, v1);
          ks0[r] = 0.f; ks1[r] = 0.f;
        }
        m0 = fmaxf(m0, __shfl_xor(m0, 16)); m0 = fmaxf(m0, __shfl_xor(m0, 32));
        m1 = fmaxf(m1, __shfl_xor(m1, 16)); m1 = fmaxf(m1, __shfl_xor(m1, 32));
        if (lane == 0) { red[wv4 * 4 + hf * 2] = m0; red[wv4 * 4 + hf * 2 + 1] = m1; }
      }
      if (kind == 2) {
        __syncthreads();
        for (int c = t; c < 640; c += 256) {  // 80 rows x 8 uint4 segs
          int row = c >> 3, seg = c & 7;
          int o = hf * 80 + row, hh = o / 40, d = o - hh * 40;
          *(uint4*)(vt_h + ((size_t)(b * 4 + hh) * 40 + d) * 4160 + s0 + seg * 8) =
              *(const uint4*)(Lv + row * 72 + seg * 8);
        }
      }
    }
  }
  __syncthreads();
  if (t < 4) {
    float m = fmaxf(fmaxf(red[t], red[4 + t]), fmaxf(red[8 + t], red[12 + t]));
    kmaxp[(b * 4 + t) * 65 + y] = m;
  }

  // ---- pad row s=4096: f[4096][c] = pe[4096] for all c => qkv = pe4096 * rowsum(W) ----
  if (y == 63) {
    float pe4 = pe[4096];
    if (t < 160) {
      int hh = t / 40, d = t - hh * 40, bh = b * 4 + hh;
#pragma unroll
      for (int kind = 0; kind < 3; ++kind) {
        const float* wsp = (kind == 0) ? wq : (kind == 1 ? wk : wv);
        const float* wr = wsp + t * 160;
        float rs = 0.f;
#pragma unroll
        for (int c4 = 0; c4 < 40; ++c4) {
          f32x4 v = *(const f32x4*)(wr + c4 * 4);
          rs += v[0] + v[1] + v[2] + v[3];
        }
        float val = pe4 * rs;
        if (kind == 0)      q_h[((size_t)bh * 4097 + 4096) * 40 + d] = (f16)(val * c1l);
        else if (kind == 1) { k_h[((size_t)bh * 4160 + 4096) * 40 + d] = (f16)val;
                              red160[t] = val * val; }
        else                vt_h[((size_t)bh * 40 + d) * 4160 + 4096] = (f16)val;
      }
    }
    __syncthreads();
    if (t < 4) {
      float s = 0.f;
#pragma unroll
      for (int j = 0; j < 40; ++j) s += red160[t * 40 + j];
      kmaxp[(b * 4 + t) * 65 + 64] = s;
    }
  }
}

// ---------------- K2: flash attention, K-split x2, packed d40, K+V LDS dbuf -------------
// grid (32,16,2) = 1024 blocks -> 4 blocks/CU. R18: (qt,bh,ks) derived from the flat
// block id so XCD = flat&7 and bh = xcd*2 + bit: each XCD's 128 resident blocks share
// only 2 bh of K/V (1.33 MB, fits 4 MB L2). Prefetch pointers increment (no per-iter
// mul/shift address chains).
__global__ __launch_bounds__(256, 4) void k_attn(
    const f16* __restrict__ q_h, const f16* __restrict__ k_h,
    const f16* __restrict__ vt_h, const float* __restrict__ kmaxp,
    float* __restrict__ pacc) {
  __shared__ __attribute__((aligned(16))) f16 Ks[2][64 * 40];
  __shared__ __attribute__((aligned(16))) f16 Vs[2][40 * 72];
  __shared__ __attribute__((aligned(16))) f16 Ones[8];
  __shared__ __attribute__((aligned(16))) f16 Zro[8];
  __shared__ __attribute__((aligned(16))) float red4[4];

  // Bijective XCD swizzle: flat = qt + 32*bh' + 512*ks' (hw dispatch order);
  // xcd ~= flat & 7. Derive logical (qt,bh,ks) so same-bh blocks co-locate per XCD.
  int flat = blockIdx.x + (blockIdx.y << 5) + (blockIdx.z << 9);
  int xcd = flat & 7, rest = flat >> 3;
  int bh = xcd * 2 + (rest & 1);
  int qt = (rest >> 1) & 31;
  int ks = rest >> 6;

  int qbase = qt * 128;
  int t = threadIdx.x, lane = t & 63, wv = t >> 6, quad = lane >> 4, col = lane & 15;
  int gbase = ks * 33;
  int nIter = 33 - ks;  // tiles 0..32 | 33..64

  if (t < 8) { Zro[t] = (f16)0; Ones[t] = (f16)1; }
  {
    float vm = (t < 65) ? kmaxp[bh * 65 + t] : 0.f;
#pragma unroll
    for (int d = 1; d < 64; d <<= 1) vm = fmaxf(vm, __shfl_xor(vm, d));
    if (lane == 0) red4[wv] = vm;
  }

  const f16* khb = k_h + ((size_t)bh * 4160 + gbase * 64) * 40;
  const f16* vtb = vt_h + (size_t)bh * 40 * 4160;
  int vrow = t >> 3, vseg = t & 7;
  uint4 rka = *(const uint4*)(khb + t * 8);
  uint4 rkb = {0, 0, 0, 0}, rvb = {0, 0, 0, 0};
  if (t < 64) rkb = *(const uint4*)(khb + (256 + t) * 8);
  uint4 rva = *(const uint4*)(vtb + vrow * 4160 + gbase * 64 + vseg * 8);
  if (t < 64) rvb = *(const uint4*)(vtb + (32 + vrow) * 4160 + gbase * 64 + vseg * 8);

  // Incrementing prefetch pointers (next tile = +64 s-rows => K +2560 elems, V +64)
  const f16* kpa = khb + 2560 + t * 8;
  const f16* kpb = khb + 2560 + (256 + t) * 8;
  const f16* vpa = vtb + (size_t)vrow * 4160 + gbase * 64 + vseg * 8 + 64;
  const f16* vpb = vpa + (size_t)32 * 4160;

  // Pre-selected LDS staging pointers (double-buffer)
  f16* ksw0 = &Ks[0][t * 8];        f16* ksw1 = &Ks[1][t * 8];
  f16* ksx0 = &Ks[0][(256 + t) * 8]; f16* ksx1 = &Ks[1][(256 + t) * 8];
  f16* vsw0 = &Vs[0][vrow * 72 + vseg * 8]; f16* vsw1 = &Vs[1][vrow * 72 + vseg * 8];
  f16* vsx0 = vsw0 + 32 * 72;       f16* vsx1 = vsw1 + 32 * 72;

  half8 zero8;
#pragma unroll
  for (int j = 0; j < 8; ++j) zero8[j] = (f16)0;

  // Q direct global->reg (q pre-scaled by c1l in K1)
  half8 bq[2][2], q32[2];
#pragma unroll
  for (int nt = 0; nt < 2; ++nt) {
    const f16* qr = q_h + ((size_t)bh * 4097 + qbase + wv * 32 + nt * 16 + col) * 40;
    bq[nt][0] = *(const half8*)(qr + quad * 8);
    q32[nt] = *(const half8*)(qr + 32);  // dims 32..39 (same row for all quads)
  }
  __syncthreads();

  float mk = fmaxf(fmaxf(red4[0], red4[1]), fmaxf(red4[2], red4[3]));

#pragma unroll
  for (int nt = 0; nt < 2; ++nt) {
    float s = 0.f;
#pragma unroll
    for (int j = 0; j < 8; ++j) {
      float a0 = (float)bq[nt][0][j];
      s += a0 * a0;
    }
    s += __shfl_xor(s, 16);   // sum dims 0..31 across quads
    s += __shfl_xor(s, 32);
#pragma unroll
    for (int j = 0; j < 8; ++j) {
      float a1 = (float)q32[nt][j];
      s += a1 * a1;           // dims 32..39 (uniform across quads)
    }
    float mfl = sqrtf(s * mk) - 14.0f;  // Delta=14 anti-subnormal boost
    half8 e = zero8;
    e[0] = (f16)(-mfl);
    // B-frag, second MFMA: quad0 = q dims 32..39; quad1 = {-mfl,0..} (pairs k40=1); else 0
    bq[nt][1] = (quad == 0) ? q32[nt] : ((quad == 1) ? e : zero8);
  }

  f32x4 o_[2][3];
#pragma unroll
  for (int a = 0; a < 2; ++a)
#pragma unroll
    for (int b2 = 0; b2 < 3; ++b2)
#pragma unroll
      for (int r = 0; r < 4; ++r) o_[a][b2][r] = 0.f;

  for (int kt = 0; kt < nIter; ++kt) {
    int bsel = kt & 1;
    int g = gbase + kt;
    *(uint4*)(bsel ? ksw1 : ksw0) = rka;
    if (t < 64) *(uint4*)(bsel ? ksx1 : ksx0) = rkb;
    *(uint4*)(bsel ? vsw1 : vsw0) = rva;
    if (t < 64) *(uint4*)(bsel ? vsx1 : vsx0) = rvb;
    if (kt + 1 < nIter) {
      rka = *(const uint4*)kpa;  kpa += 2560;
      if (t < 64) { rkb = *(const uint4*)kpb; }
      kpb += 2560;
      rva = *(const uint4*)vpa;  vpa += 64;
      if (t < 64) { rvb = *(const uint4*)vpb; }
      vpb += 64;
    }
    __syncthreads();

    bool lastt = (g == 64);  // wave-uniform, true once (ks==1 final iter)

    // ---- phase A: all QK^T (8 independent MFMAs) ----
    f32x4 acc[4][2];  // [mt][nt]
#pragma unroll
    for (int mt = 0; mt < 4; ++mt) {
      int row = mt * 16 + col;
      half8 ak0 = *(half8*)(&Ks[bsel][row * 40 + quad * 8]);
      const f16* pa1 = (quad == 0) ? &Ks[bsel][row * 40 + 32]
                                   : ((quad == 1) ? Ones : Zro);
      half8 ak1 = *(half8*)pa1;
#pragma unroll
      for (int nt = 0; nt < 2; ++nt) {
        f32x4 a; a[0] = 0.f; a[1] = 0.f; a[2] = 0.f; a[3] = 0.f;
        a = MFMA16(ak0, bq[nt][0], a);
        a = MFMA16(ak1, bq[nt][1], a);
        acc[mt][nt] = a;
      }
    }

    // ---- phase B: exp2 + pack + cross-quad redistribute (one VALU burst) ----
    half8 pa[2][2];  // [kk2][nt]
#pragma unroll
    for (int kk2 = 0; kk2 < 2; ++kk2)
#pragma unroll
      for (int nt = 0; nt < 2; ++nt) {
        float p0[4], p1[4];
#pragma unroll
        for (int r = 0; r < 4; ++r) {
          p0[r] = __builtin_amdgcn_exp2f(acc[kk2 * 2][nt][r]);
          p1[r] = __builtin_amdgcn_exp2f(acc[kk2 * 2 + 1][nt][r]);
        }
        if (__builtin_expect(lastt, 0)) {  // poison rows: keep only k-elem 0 (s=4096)
#pragma unroll
          for (int r = 0; r < 4; ++r) {
            p0[r] = (kk2 == 0 && (quad * 4 + r) == 0) ? p0[r] : 0.f;
            p1[r] = 0.f;
          }
        }
        unsigned sr[4];
        sr[0] = pk2(p0[0], p0[1]);
        sr[1] = pk2(p0[2], p0[3]);
        sr[2] = pk2(p1[0], p1[1]);
        sr[3] = pk2(p1[2], p1[3]);
        plswap_pair(sr[0], sr[2]);  // -> frag regs 0 and 2
        plswap_pair(sr[1], sr[3]);  // -> frag regs 1 and 3
        u32x4 uu; uu[0] = sr[0]; uu[1] = sr[1]; uu[2] = sr[2]; uu[3] = sr[3];
        pa[kk2][nt] = __builtin_bit_cast(half8, uu);
      }

    // ---- phase C: all PV (12 MFMAs) ----
#pragma unroll
    for (int kk2 = 0; kk2 < 2; ++kk2)
#pragma unroll
      for (int nv = 0; nv < 3; ++nv) {
        int d = nv * 16 + col;
        const f16* vp = (d < 40) ? &Vs[bsel][d * 72 + kk2 * 32 + quad * 8]
                                 : ((d == 40) ? Ones : Zro);
        half8 bv = *(half8*)vp;
        o_[0][nv] = MFMA16(pa[kk2][0], bv, o_[0][nv]);
        o_[1][nv] = MFMA16(pa[kk2][1], bv, o_[1][nv]);
      }
  }

  float* pb = pacc + (size_t)(ks * 16 + bh) * 4096 * 48;
#pragma unroll
  for (int mtq = 0; mtq < 2; ++mtq)
#pragma unroll
    for (int nv = 0; nv < 3; ++nv)
#pragma unroll
      for (int r = 0; r < 4; ++r) {
        int q = qbase + wv * 32 + mtq * 16 + quad * 4 + r;
        pb[(size_t)q * 48 + nv * 16 + col] = o_[mtq][nv][r];
      }
}

// ---------------- K3: combine K-split partials + LayerNorm + residual + upsample --------
// grid (64 y, 4 b, 2 z): block handles 32 w-rows (w = z*32..z*32+31), writes X in
// [z*64, z*64+64) of out rows 2y, 2y+1. Vectorized f32x4 pacc reads; 512 blocks (2/CU).
__global__ __launch_bounds__(256) void k_ln_out(
    const float* __restrict__ pacc, const float* __restrict__ lnw,
    const float* __restrict__ lnb, float* __restrict__ out) {
  __shared__ float g[32 * 164];
  __shared__ float linv[32 * 4];
  int y = blockIdx.x, b = blockIdx.y, z = blockIdx.z, t = threadIdx.x;
  const size_t P1 = (size_t)16 * 4096 * 48;
  int w0 = z * 32;
  if (t < 128) {
    int row = t >> 2, h = t & 3;
    size_t i0 = ((size_t)(b * 4 + h) * 4096 + y * 64 + w0 + row) * 48 + 40;
    linv[row * 4 + h] = 1.f / (pacc[i0] + pacc[P1 + i0]);
  }
  __syncthreads();
#pragma unroll
  for (int it = 0; it < 5; ++it) {
    int flat = t + it * 256;  // [0,1280) f32x4 units
    int row = flat / 40, dq = flat - row * 40;
    int h = dq / 10, d = (dq - h * 10) * 4;
    size_t idx = ((size_t)(b * 4 + h) * 4096 + y * 64 + w0 + row) * 48 + d;
    f32x4 v0 = *(const f32x4*)(pacc + idx);
    f32x4 v1 = *(const f32x4*)(pacc + P1 + idx);
    float li = linv[row * 4 + h];
    f32x4 gv;
#pragma unroll
    for (int j = 0; j < 4; ++j) gv[j] = (v0[j] + v1[j]) * li;
    *(f32x4*)(g + row * 164 + h * 40 + d) = gv;
  }
  __syncthreads();
  int row = t >> 3, part = t & 7;  // 32 rows x 8 parts x 20 cols
  float* gr = g + row * 164 + part * 20;
  float s1 = 0.f, s2 = 0.f;
#pragma unroll
  for (int j4 = 0; j4 < 5; ++j4) {
    f32x4 v = *(f32x4*)(gr + j4 * 4);
#pragma unroll
    for (int j = 0; j < 4; ++j) { s1 += v[j]; s2 += v[j] * v[j]; }
  }
  s1 += __shfl_xor(s1, 1); s1 += __shfl_xor(s1, 2); s1 += __shfl_xor(s1, 4);
  s2 += __shfl_xor(s2, 1); s2 += __shfl_xor(s2, 2); s2 += __shfl_xor(s2, 4);
  float mu = s1 * (1.f / 160.f);
  float var = s2 * (1.f / 160.f) - mu * mu;
  float inv = rsqrtf(var + 1e-5f);
  const float* lw = lnw + part * 20;
  const float* lb = lnb + part * 20;
#pragma unroll
  for (int j = 0; j < 20; ++j) {
    float v = gr[j];
    gr[j] = (v - mu) * inv * lw[j] + lb[j] + v;
  }
  __syncthreads();
  int Yo = t >> 7, xp = t & 63, cpar = (t >> 6) & 1;
  int rl = xp >> 1;
  float* ob = out + (2 * y + Yo) * 128 + z * 64 + xp;
  for (int c = cpar; c < 160; c += 2)
    ob[(size_t)(b * 160 + c) * 16384] = g[rl * 164 + c];
}

extern "C" void kernel_launch(void* const* d_in, const int* in_sizes, int n_in,
                              void* d_out, int out_size, void* d_ws, size_t ws_size,
                              hipStream_t stream) {
  const float* x   = (const float*)d_in[0];
  const float* w1  = (const float*)d_in[1];
  const float* b1  = (const float*)d_in[2];
  const float* w2  = (const float*)d_in[3];
  const float* b2  = (const float*)d_in[4];
  const float* pe  = (const float*)d_in[5];
  const float* wq  = (const float*)d_in[6];
  const float* wk  = (const float*)d_in[7];
  const float* wvp = (const float*)d_in[8];
  const float* lnw = (const float*)d_in[9];
  const float* lnb = (const float*)d_in[10];
  float* out = (float*)d_out;

  char* p = (char*)d_ws;
  f16* q_h   = (f16*)p;   p += (size_t)16 * 4097 * 40 * 2;       // 5,244,160
  f16* k_h   = (f16*)p;   p += (size_t)16 * 4160 * 40 * 2;       // 5,324,800
  f16* vt_h  = (f16*)p;   p += (size_t)16 * 40 * 4160 * 2;       // 5,324,800
  float* pacc = (float*)p; p += (size_t)2 * 16 * 4096 * 48 * 4;  // 25,165,824
  float* kmaxp = (float*)p; p += 16 * 65 * 4;                    // 4,160
  // total ~41.1 MB

  k_convqkv<<<dim3(64, 4), 256, 0, stream>>>(x, w1, b1, w2, b2, pe, wq, wk, wvp,
                                             q_h, k_h, vt_h, kmaxp);
  k_attn<<<dim3(32, 16, 2), 256, 0, stream>>>(q_h, k_h, vt_h, kmaxp, pacc);
  k_ln_out<<<dim3(64, 4, 2), 256, 0, stream>>>(pacc, lnw, lnb, out);
}